// Round 10
// baseline (38.414 us; speedup 1.0000x reference)
//
#include <hip/hip_runtime.h>
#include <hip/hip_bf16.h>
#include <math.h>

#define B_   4
#define C_   64
#define N_   4096
#define L2E  1.4426950408889634f

typedef __attribute__((ext_vector_type(8)))  short bf16x8;
typedef __attribute__((ext_vector_type(4)))  float f32x4;
typedef __attribute__((ext_vector_type(16))) float f32x16;
typedef __attribute__((ext_vector_type(4)))  uint  uint4v;

#define MFMA16(a,b,c) __builtin_amdgcn_mfma_f32_16x16x32_bf16(a,b,c,0,0,0)
#define MFMA32(a,b,c) __builtin_amdgcn_mfma_f32_32x32x16_bf16(a,b,c,0,0,0)

static __device__ inline ushort f2bf(float f) {
    __hip_bfloat16 h = __float2bfloat16(f);
    return *reinterpret_cast<ushort*>(&h);
}
static __device__ inline uint packbf(float a, float b) {
    return (uint)f2bf(a) | ((uint)f2bf(b) << 16);
}
static __device__ inline uint cvtpk(float lo, float hi) {
    uint r;
    asm("v_cvt_pk_bf16_f32 %0, %1, %2" : "=v"(r) : "v"(lo), "v"(hi));
    return r;
}
static __device__ inline void plswap(uint &a, uint &b) {
    asm("v_permlane32_swap_b32 %0, %1" : "+v"(a), "+v"(b));
}
static __device__ inline float tmax16(const f32x16 &s) {
    float a0 = fmaxf(s[0], s[1]),  a1 = fmaxf(s[2], s[3]);
    float a2 = fmaxf(s[4], s[5]),  a3 = fmaxf(s[6], s[7]);
    float a4 = fmaxf(s[8], s[9]),  a5 = fmaxf(s[10], s[11]);
    float a6 = fmaxf(s[12], s[13]), a7 = fmaxf(s[14], s[15]);
    a0 = fmaxf(a0, a1); a2 = fmaxf(a2, a3); a4 = fmaxf(a4, a5); a6 = fmaxf(a6, a7);
    return fmaxf(fmaxf(a0, a2), fmaxf(a4, a6));
}
static __device__ inline float tsum16(const f32x16 &s) {
    float a0 = s[0] + s[1],  a1 = s[2] + s[3];
    float a2 = s[4] + s[5],  a3 = s[6] + s[7];
    float a4 = s[8] + s[9],  a5 = s[10] + s[11];
    float a6 = s[12] + s[13], a7 = s[14] + s[15];
    a0 += a1; a2 += a3; a4 += a5; a6 += a7;
    return (a0 + a2) + (a4 + a6);
}

// ---------------- QKV projection: zero-LDS, zero-barrier ----------------
// OUT[96,N] = W[96,64] @ X[64,N]; out-tiles ot 0..5 (0=Q from xrgb xL2E,
// 1=K, 2..5=V quarters). Block = 256 thr = 4 waves = (pw px-half) x
// (oh ot-half); each wave computes 3 full out-tiles at k=64 (2 chained
// MFMAs) for its 16 pixels and stores directly with bias. No LDS/barriers.
__global__ __launch_bounds__(256) void qkv_mfma(
    const float* __restrict__ x, const float* __restrict__ xrgb,
    const float* __restrict__ Wq, const float* __restrict__ bq,
    const float* __restrict__ Wk, const float* __restrict__ bk,
    const float* __restrict__ Wv, const float* __restrict__ bv,
    ushort* __restrict__ Qo, ushort* __restrict__ Ko, ushort* __restrict__ Vo)
{
    const int t = threadIdx.x, b = blockIdx.y, n0 = blockIdx.x * 32;
    const int w = t >> 6, lane = t & 63, li = lane & 15, g = lane >> 4;
    const int pw = w & 1, oh = w >> 1;

    const int px = n0 + pw * 16 + li;

    // B-fragments (full k=64): bf[kk], k = kk*32 + g*8 + r
    bf16x8 bxf[2], brf[2];
    #pragma unroll
    for (int kk = 0; kk < 2; ++kk) {
        const int c0 = kk * 32 + g * 8;
        const float* xb = x + ((size_t)b * C_ + c0) * N_ + px;
        #pragma unroll
        for (int r = 0; r < 8; ++r) bxf[kk][r] = (short)f2bf(xb[(size_t)r * N_]);
        if (oh == 0) {
            const float* rb = xrgb + ((size_t)b * C_ + c0) * N_ + px;
            #pragma unroll
            for (int r = 0; r < 8; ++r) brf[kk][r] = (short)f2bf(rb[(size_t)r * N_]);
        }
    }

    const f32x4 cz = {0.f, 0.f, 0.f, 0.f};
    #pragma unroll
    for (int j = 0; j < 3; ++j) {
        const int ot = oh * 3 + j;
        // A fragment rows: W row = (ot<2 ? li : (ot-2)*16+li), k = kk*32+g*8+r
        const float* wsrc;
        const float* bsrc;
        if (ot == 0)      { wsrc = Wq + li * 64;              bsrc = bq; }
        else if (ot == 1) { wsrc = Wk + li * 64;              bsrc = bk; }
        else              { wsrc = Wv + ((ot - 2) * 16 + li) * 64; bsrc = bv + (ot - 2) * 16; }
        const float s = (ot == 0) ? L2E : 1.0f;   // fold log2e into Q

        f32x4 acc = cz;
        #pragma unroll
        for (int kk = 0; kk < 2; ++kk) {
            const int c0 = kk * 32 + g * 8;
            const float4 a  = *(const float4*)(wsrc + c0);
            const float4 c4 = *(const float4*)(wsrc + c0 + 4);
            bf16x8 wa;
            wa[0] = (short)f2bf(a.x * s);  wa[1] = (short)f2bf(a.y * s);
            wa[2] = (short)f2bf(a.z * s);  wa[3] = (short)f2bf(a.w * s);
            wa[4] = (short)f2bf(c4.x * s); wa[5] = (short)f2bf(c4.y * s);
            wa[6] = (short)f2bf(c4.z * s); wa[7] = (short)f2bf(c4.w * s);
            acc = MFMA16(wa, (ot == 0 ? brf[kk] : bxf[kk]), acc);
        }
        // bias + store; lane (li,g) holds out-ch o = g*4+r (within tile), px
        const float b0 = bsrc[g * 4 + 0] * s, b1 = bsrc[g * 4 + 1] * s;
        const float b2 = bsrc[g * 4 + 2] * s, b3 = bsrc[g * 4 + 3] * s;
        if (ot < 2) {
            uint2 pwd;
            pwd.x = packbf(acc[0] + b0, acc[1] + b1);
            pwd.y = packbf(acc[2] + b2, acc[3] + b3);
            ushort* dst = (ot == 0 ? Qo : Ko) + (size_t)(b * N_ + px) * 16 + g * 4;
            *(uint2*)dst = pwd;
        } else {
            // VT[b][jt=px>>4][ch=(ot-2)*16+g*4+r][jin=px&15]
            const size_t base = (((size_t)b * (N_ / 16) + (px >> 4)) * 64
                                 + (ot - 2) * 16 + g * 4) * 16 + (px & 15);
            Vo[base]      = f2bf(acc[0] + b0);
            Vo[base + 16] = f2bf(acc[1] + b1);
            Vo[base + 32] = f2bf(acc[2] + b2);
            Vo[base + 48] = f2bf(acc[3] + b3);
        }
    }
}

// ---------------- flash attention, 32x32 MFMA, low-pressure loop ----------
// 512 thr = 8 waves; wave w owns N/8=512 keys, processed as 16 sequential
// 32-key tiles (ONE f32x16 S-state + 4 V-frags live at a time -> ~85 VGPR,
// no spill at the (512,4)=128 cap). K/V fragments coalesced from L2 (VT
// fragment-major). P in-register via cvt_pk+permlane32_swap (T12).
// Zero-LDS, zero-barrier main loop; 2-barrier merge tail.
#define JG_   8
#define OTP   36
#define SMEM_FL (73728 + 1056 + 1056 + 128)

__global__ __launch_bounds__(512, 4) void flash32(
    const ushort* __restrict__ Qg, const ushort* __restrict__ Kg,
    const ushort* __restrict__ VT, const float* __restrict__ x,
    const float* __restrict__ lam, float* __restrict__ out)
{
    __shared__ __align__(16) char smem[SMEM_FL];
    float*  OT = (float*)smem;                       // [8][64][OTP]
    float*  MC = (float*)(smem + 73728);             // [8][33]
    float*  LC = (float*)(smem + 73728 + 1056);      // [8][33]
    float*  IV = (float*)(smem + 73728 + 2112);      // [32]

    const int t = threadIdx.x, w = t >> 6, lane = t & 63;
    const int l31 = lane & 31, h = lane >> 5;

    // XCD-locality remap: batch b's 128 blocks land on 2 XCDs (K/V L2-local)
    const int wg = blockIdx.x;
    const int b  = (wg & 7) >> 1;
    const int it = ((wg >> 3) << 1) | (wg & 1);
    const int i0 = it * 32;

    const bf16x8 qf = *(const bf16x8*)(Qg + ((size_t)(b * N_ + i0 + l31)) * 16 + h * 8);

    const size_t jbase = (size_t)w * (N_ / JG_);
    const ushort* kp = Kg + ((size_t)(b * N_) + jbase + l31) * 16 + h * 8;
    const ushort* vt = VT + (((size_t)b * (N_ / 16) + jbase / 16) * 64 + l31) * 16 + h * 8;

    f32x16 acc0, acc1, z16;
    #pragma unroll
    for (int i = 0; i < 16; ++i) { acc0[i] = 0.f; acc1[i] = 0.f; z16[i] = 0.f; }
    float m_run = -1e30f, l_loc = 0.f;

    #pragma unroll 1
    for (int jt = 0; jt < 16; ++jt) {          // 16 tiles of 32 keys
        // ---- energy: one 32-key S-tile (K=16 exact) ----
        const bf16x8 kf = *(const bf16x8*)(kp + (size_t)(jt * 32) * 16);
        f32x16 st = MFMA32(kf, qf, z16);

        // ---- online max + defer-rescale (T13) ----
        float m_c = tmax16(st);
        m_c = fmaxf(m_c, __shfl_xor(m_c, 32));
        if (__any(m_c > m_run + 8.f)) {
            const float m_new = fmaxf(m_run, m_c);
            const float sc = exp2f(m_run - m_new);
            l_loc *= sc;
            #pragma unroll
            for (int i = 0; i < 16; ++i) { acc0[i] *= sc; acc1[i] *= sc; }
            m_run = m_new;
        }

        // ---- exp2 + sum ----
        #pragma unroll
        for (int i = 0; i < 16; ++i) st[i] = exp2f(st[i] - m_run);
        l_loc += tsum16(st);

        // ---- P -> bf16 PV-fragments in-register (T12) ----
        uint A0 = cvtpk(st[0],  st[1]),  A1 = cvtpk(st[2],  st[3]);
        uint B0 = cvtpk(st[4],  st[5]),  B1 = cvtpk(st[6],  st[7]);
        uint C0 = cvtpk(st[8],  st[9]),  C1 = cvtpk(st[10], st[11]);
        uint D0 = cvtpk(st[12], st[13]), D1 = cvtpk(st[14], st[15]);
        plswap(A0, B0); plswap(A1, B1); plswap(C0, D0); plswap(C1, D1);
        uint4v u0 = {A0, A1, B0, B1}, u1 = {C0, C1, D0, D1};
        const bf16x8 pf0 = __builtin_bit_cast(bf16x8, u0);
        const bf16x8 pf1 = __builtin_bit_cast(bf16x8, u1);

        // ---- PV: 4 MFMAs, V fragments straight from L2 (VT layout) ----
        const ushort* vtj = vt + (size_t)jt * 2048;   // 32 keys = 2 x 16j tiles
        const bf16x8 va0 = *(const bf16x8*)(vtj);
        const bf16x8 vb0 = *(const bf16x8*)(vtj + 512);
        const bf16x8 va1 = *(const bf16x8*)(vtj + 1024);
        const bf16x8 vb1 = *(const bf16x8*)(vtj + 1536);
        acc0 = MFMA32(va0, pf0, acc0);
        acc1 = MFMA32(vb0, pf0, acc1);
        acc0 = MFMA32(va1, pf1, acc0);
        acc1 = MFMA32(vb1, pf1, acc1);
    }
    const float l_run = l_loc + __shfl_xor(l_loc, 32);

    // ---- merge 8 j-partials ----
    if (h == 0) { MC[w * 33 + l31] = m_run; LC[w * 33 + l31] = l_run; }
    __syncthreads();                        // bar0

    float mp[8];
    #pragma unroll
    for (int p = 0; p < 8; ++p) mp[p] = MC[p * 33 + l31];
    float ms = mp[0];
    #pragma unroll
    for (int p = 1; p < 8; ++p) ms = fmaxf(ms, mp[p]);
    float lsum = 0.f, wt_own = 0.f;
    #pragma unroll
    for (int p = 0; p < 8; ++p) {
        const float wt = exp2f(mp[p] - ms);
        lsum += wt * LC[p * 33 + l31];
        if (p == w) wt_own = wt;
    }
    if (w == 0 && h == 0) IV[l31] = lam[0] / lsum;

    #pragma unroll
    for (int r = 0; r < 16; ++r) {
        const int c = (r & 3) + 8 * (r >> 2) + 4 * h;
        OT[(w * 64 + c) * OTP + l31]      = acc0[r] * wt_own;
        OT[(w * 64 + c + 32) * OTP + l31] = acc1[r] * wt_own;
    }
    __syncthreads();                        // bar1

    // ---- epilogue: out = sum_p OT[p] * IV + x ----
    {
        const int c = t >> 3, sg = t & 7;
        f32x4 o = {0.f, 0.f, 0.f, 0.f};
        #pragma unroll
        for (int p = 0; p < 8; ++p) {
            const f32x4 v = *(const f32x4*)&OT[(p * 64 + c) * OTP + sg * 4];
            o[0] += v[0]; o[1] += v[1]; o[2] += v[2]; o[3] += v[3];
        }
        const size_t off = ((size_t)b * C_ + c) * N_ + i0 + sg * 4;
        const float4 xv = *(const float4*)(x + off);
        float4 res;
        res.x = o[0] * IV[sg * 4 + 0] + xv.x;
        res.y = o[1] * IV[sg * 4 + 1] + xv.y;
        res.z = o[2] * IV[sg * 4 + 2] + xv.z;
        res.w = o[3] * IV[sg * 4 + 3] + xv.w;
        *(float4*)(out + off) = res;
    }
}

extern "C" void kernel_launch(void* const* d_in, const int* in_sizes, int n_in,
                              void* d_out, int out_size, void* d_ws, size_t ws_size,
                              hipStream_t stream)
{
    (void)in_sizes; (void)n_in; (void)out_size; (void)ws_size;
    const float* x    = (const float*)d_in[0];
    const float* xrgb = (const float*)d_in[1];
    const float* Wq   = (const float*)d_in[2];
    const float* bq   = (const float*)d_in[3];
    const float* Wk   = (const float*)d_in[4];
    const float* bk   = (const float*)d_in[5];
    const float* Wv   = (const float*)d_in[6];
    const float* bv   = (const float*)d_in[7];
    const float* lam  = (const float*)d_in[8];
    float* out = (float*)d_out;

    // workspace (bf16): Q 512KB | K 512KB | VT 2MB — all fully overwritten
    ushort* Qw = (ushort*)d_ws;                       // [B][N][16]
    ushort* Kw = Qw + (size_t)B_ * N_ * 16;           // [B][N][16]
    ushort* Vw = Kw + (size_t)B_ * N_ * 16;           // VT[B][N/16][64][16]

    qkv_mfma<<<dim3(N_ / 32, B_), 256, 0, stream>>>(
        x, xrgb, Wq, bq, Wk, bk, Wv, bv, Qw, Kw, Vw);

    flash32<<<dim3(512), 512, 0, stream>>>(
        Qw, Kw, Vw, x, lam, out);
}

// Round 12
// 37.946 us; speedup vs baseline: 1.0123x; 1.0123x over previous
//
#include <hip/hip_runtime.h>
#include <hip/hip_bf16.h>
#include <math.h>

#define B_   4
#define C_   64
#define N_   4096
#define L2E  1.4426950408889634f

typedef __attribute__((ext_vector_type(8)))  short bf16x8;
typedef __attribute__((ext_vector_type(4)))  float f32x4;
typedef __attribute__((ext_vector_type(16))) float f32x16;
typedef __attribute__((ext_vector_type(4)))  uint  uint4v;

#define MFMA16(a,b,c) __builtin_amdgcn_mfma_f32_16x16x32_bf16(a,b,c,0,0,0)
#define MFMA32(a,b,c) __builtin_amdgcn_mfma_f32_32x32x16_bf16(a,b,c,0,0,0)

static __device__ inline ushort f2bf(float f) {
    __hip_bfloat16 h = __float2bfloat16(f);
    return *reinterpret_cast<ushort*>(&h);
}
static __device__ inline uint packbf(float a, float b) {
    return (uint)f2bf(a) | ((uint)f2bf(b) << 16);
}
static __device__ inline uint cvtpk(float lo, float hi) {
    uint r;
    asm("v_cvt_pk_bf16_f32 %0, %1, %2" : "=v"(r) : "v"(lo), "v"(hi));
    return r;
}
static __device__ inline void plswap(uint &a, uint &b) {
    asm("v_permlane32_swap_b32 %0, %1" : "+v"(a), "+v"(b));
}
static __device__ inline float tsum16(const f32x16 &s) {
    float a0 = s[0] + s[1],  a1 = s[2] + s[3];
    float a2 = s[4] + s[5],  a3 = s[6] + s[7];
    float a4 = s[8] + s[9],  a5 = s[10] + s[11];
    float a6 = s[12] + s[13], a7 = s[14] + s[15];
    a0 += a1; a2 += a3; a4 += a5; a6 += a7;
    return (a0 + a2) + (a4 + a6);
}

// ---------------- QKV projection: zero-LDS, zero-barrier (R10, validated) ---
__global__ __launch_bounds__(256) void qkv_mfma(
    const float* __restrict__ x, const float* __restrict__ xrgb,
    const float* __restrict__ Wq, const float* __restrict__ bq,
    const float* __restrict__ Wk, const float* __restrict__ bk,
    const float* __restrict__ Wv, const float* __restrict__ bv,
    ushort* __restrict__ Qo, ushort* __restrict__ Ko, ushort* __restrict__ Vo)
{
    const int t = threadIdx.x, b = blockIdx.y, n0 = blockIdx.x * 32;
    const int w = t >> 6, lane = t & 63, li = lane & 15, g = lane >> 4;
    const int pw = w & 1, oh = w >> 1;

    const int px = n0 + pw * 16 + li;

    bf16x8 bxf[2], brf[2];
    #pragma unroll
    for (int kk = 0; kk < 2; ++kk) {
        const int c0 = kk * 32 + g * 8;
        const float* xb = x + ((size_t)b * C_ + c0) * N_ + px;
        #pragma unroll
        for (int r = 0; r < 8; ++r) bxf[kk][r] = (short)f2bf(xb[(size_t)r * N_]);
        if (oh == 0) {
            const float* rb = xrgb + ((size_t)b * C_ + c0) * N_ + px;
            #pragma unroll
            for (int r = 0; r < 8; ++r) brf[kk][r] = (short)f2bf(rb[(size_t)r * N_]);
        } else {
            brf[kk] = bxf[kk];   // never used for ot!=0, keep defined
        }
    }

    const f32x4 cz = {0.f, 0.f, 0.f, 0.f};
    #pragma unroll
    for (int j = 0; j < 3; ++j) {
        const int ot = oh * 3 + j;
        const float* wsrc;
        const float* bsrc;
        if (ot == 0)      { wsrc = Wq + li * 64;                   bsrc = bq; }
        else if (ot == 1) { wsrc = Wk + li * 64;                   bsrc = bk; }
        else              { wsrc = Wv + ((ot - 2) * 16 + li) * 64; bsrc = bv + (ot - 2) * 16; }
        const float s = (ot == 0) ? L2E : 1.0f;   // fold log2e into Q

        f32x4 acc = cz;
        #pragma unroll
        for (int kk = 0; kk < 2; ++kk) {
            const int c0 = kk * 32 + g * 8;
            const float4 a  = *(const float4*)(wsrc + c0);
            const float4 c4 = *(const float4*)(wsrc + c0 + 4);
            bf16x8 wa;
            wa[0] = (short)f2bf(a.x * s);  wa[1] = (short)f2bf(a.y * s);
            wa[2] = (short)f2bf(a.z * s);  wa[3] = (short)f2bf(a.w * s);
            wa[4] = (short)f2bf(c4.x * s); wa[5] = (short)f2bf(c4.y * s);
            wa[6] = (short)f2bf(c4.z * s); wa[7] = (short)f2bf(c4.w * s);
            acc = MFMA16(wa, (ot == 0 ? brf[kk] : bxf[kk]), acc);
        }
        const float b0 = bsrc[g * 4 + 0] * s, b1 = bsrc[g * 4 + 1] * s;
        const float b2 = bsrc[g * 4 + 2] * s, b3 = bsrc[g * 4 + 3] * s;
        if (ot < 2) {
            uint2 pwd;
            pwd.x = packbf(acc[0] + b0, acc[1] + b1);
            pwd.y = packbf(acc[2] + b2, acc[3] + b3);
            ushort* dst = (ot == 0 ? Qo : Ko) + (size_t)(b * N_ + px) * 16 + g * 4;
            *(uint2*)dst = pwd;
        } else {
            const size_t base = (((size_t)b * (N_ / 16) + (px >> 4)) * 64
                                 + (ot - 2) * 16 + g * 4) * 16 + (px & 15);
            Vo[base]      = f2bf(acc[0] + b0);
            Vo[base + 16] = f2bf(acc[1] + b1);
            Vo[base + 32] = f2bf(acc[2] + b2);
            Vo[base + 48] = f2bf(acc[3] + b3);
        }
    }
}

// ---------------- flash attention: fixed-shift softmax + Q-pairing ----------
// Softmax is shift-invariant; |s*log2e| < ~10 << 126 so P = exp2(st) RAW is
// overflow-safe -> no max tracking, no rescale, no cross-lane max. Merge is a
// pure SUM. Wave holds TWO Q-fragments (64 queries), reuses each K/V fragment
// for both -> L2 traffic halves. exp2f() ONLY (compiler-emitted v_exp_f32 with
// TRANS-hazard handling; R11's inline-asm exp produced NaN = stale-read).
__global__ __launch_bounds__(512, 2) void flash32(
    const ushort* __restrict__ Qg, const ushort* __restrict__ Kg,
    const ushort* __restrict__ VT, const float* __restrict__ x,
    const float* __restrict__ lam, float* __restrict__ out)
{
    __shared__ float OT[8][64][36];   // 73728 B (per-wave partial O)
    __shared__ float LC[2][8][33];    // 2112 B  (per-half partial l)

    const int t = threadIdx.x, w = t >> 6, lane = t & 63;
    const int l31 = lane & 31, h = lane >> 5;

    const int wg = blockIdx.x;
    const int b  = wg >> 6;           // each batch's K/V (1.25MB bf16) is L2-warm
    const int i0 = (wg & 63) * 64;

    // two Q fragments: queries i0+l31 and i0+32+l31 (B op: col=i, k=h*8+r)
    const bf16x8 qfA = *(const bf16x8*)(Qg + ((size_t)(b * N_ + i0 + l31)) * 16 + h * 8);
    const bf16x8 qfB = *(const bf16x8*)(Qg + ((size_t)(b * N_ + i0 + 32 + l31)) * 16 + h * 8);

    const size_t jbase = (size_t)w * (N_ / 8);
    const ushort* kp = Kg + ((size_t)(b * N_) + jbase + l31) * 16 + h * 8;
    const ushort* vt = VT + (((size_t)b * (N_ / 16) + jbase / 16) * 64 + l31) * 16 + h * 8;

    f32x16 aA0, aA1, aB0, aB1, z16;
    #pragma unroll
    for (int i = 0; i < 16; ++i) {
        aA0[i] = 0.f; aA1[i] = 0.f; aB0[i] = 0.f; aB1[i] = 0.f; z16[i] = 0.f;
    }
    float lA = 0.f, lB = 0.f;

    #pragma unroll 1
    for (int jt = 0; jt < 16; ++jt) {          // 16 tiles of 32 keys
        const bf16x8 kf = *(const bf16x8*)(kp + (size_t)jt * 512);
        const ushort* vtj = vt + (size_t)jt * 2048;
        const bf16x8 va0 = *(const bf16x8*)(vtj);
        const bf16x8 vb0 = *(const bf16x8*)(vtj + 512);
        const bf16x8 va1 = *(const bf16x8*)(vtj + 1024);
        const bf16x8 vb1 = *(const bf16x8*)(vtj + 1536);

        // ---- half A ----
        {
            f32x16 st = MFMA32(kf, qfA, z16);
            #pragma unroll
            for (int i = 0; i < 16; ++i) st[i] = exp2f(st[i]);   // raw 2^s
            lA += tsum16(st);
            uint A0 = cvtpk(st[0],  st[1]),  A1 = cvtpk(st[2],  st[3]);
            uint B0 = cvtpk(st[4],  st[5]),  B1 = cvtpk(st[6],  st[7]);
            uint C0 = cvtpk(st[8],  st[9]),  C1 = cvtpk(st[10], st[11]);
            uint D0 = cvtpk(st[12], st[13]), D1 = cvtpk(st[14], st[15]);
            plswap(A0, B0); plswap(A1, B1); plswap(C0, D0); plswap(C1, D1);
            uint4v u0 = {A0, A1, B0, B1}, u1 = {C0, C1, D0, D1};
            const bf16x8 pf0 = __builtin_bit_cast(bf16x8, u0);
            const bf16x8 pf1 = __builtin_bit_cast(bf16x8, u1);
            aA0 = MFMA32(va0, pf0, aA0);
            aA1 = MFMA32(vb0, pf0, aA1);
            aA0 = MFMA32(va1, pf1, aA0);
            aA1 = MFMA32(vb1, pf1, aA1);
        }
        // ---- half B (reuses kf + V fragments) ----
        {
            f32x16 st = MFMA32(kf, qfB, z16);
            #pragma unroll
            for (int i = 0; i < 16; ++i) st[i] = exp2f(st[i]);
            lB += tsum16(st);
            uint A0 = cvtpk(st[0],  st[1]),  A1 = cvtpk(st[2],  st[3]);
            uint B0 = cvtpk(st[4],  st[5]),  B1 = cvtpk(st[6],  st[7]);
            uint C0 = cvtpk(st[8],  st[9]),  C1 = cvtpk(st[10], st[11]);
            uint D0 = cvtpk(st[12], st[13]), D1 = cvtpk(st[14], st[15]);
            plswap(A0, B0); plswap(A1, B1); plswap(C0, D0); plswap(C1, D1);
            uint4v u0 = {A0, A1, B0, B1}, u1 = {C0, C1, D0, D1};
            const bf16x8 pf0 = __builtin_bit_cast(bf16x8, u0);
            const bf16x8 pf1 = __builtin_bit_cast(bf16x8, u1);
            aB0 = MFMA32(va0, pf0, aB0);
            aB1 = MFMA32(vb0, pf0, aB1);
            aB0 = MFMA32(va1, pf1, aB0);
            aB1 = MFMA32(vb1, pf1, aB1);
        }
    }

    // per-query l: combine the two C/D row-halves (h=0/1)
    lA += __shfl_xor(lA, 32);
    lB += __shfl_xor(lB, 32);
    if (h == 0) { LC[0][w][l31] = lA; LC[1][w][l31] = lB; }

    const float la = lam[0];

    // ---- round A: sum-merge 8 partials, queries i0..i0+31 ----
    #pragma unroll
    for (int r = 0; r < 16; ++r) {
        const int c = (r & 3) + 8 * (r >> 2) + 4 * h;
        OT[w][c][l31]      = aA0[r];
        OT[w][c + 32][l31] = aA1[r];
    }
    __syncthreads();
    {
        const int c = t >> 3, q0 = (t & 7) * 4;
        f32x4 o = {0.f, 0.f, 0.f, 0.f};
        f32x4 ls = {0.f, 0.f, 0.f, 0.f};
        #pragma unroll
        for (int p = 0; p < 8; ++p) {
            const f32x4 v = *(const f32x4*)&OT[p][c][q0];
            o[0] += v[0]; o[1] += v[1]; o[2] += v[2]; o[3] += v[3];
            #pragma unroll
            for (int k = 0; k < 4; ++k) ls[k] += LC[0][p][q0 + k];
        }
        const size_t off = ((size_t)b * C_ + c) * N_ + i0 + q0;
        const float4 xv = *(const float4*)(x + off);
        float4 res;
        res.x = la * o[0] / ls[0] + xv.x;
        res.y = la * o[1] / ls[1] + xv.y;
        res.z = la * o[2] / ls[2] + xv.z;
        res.w = la * o[3] / ls[3] + xv.w;
        *(float4*)(out + off) = res;
    }
    __syncthreads();

    // ---- round B: queries i0+32..i0+63 ----
    #pragma unroll
    for (int r = 0; r < 16; ++r) {
        const int c = (r & 3) + 8 * (r >> 2) + 4 * h;
        OT[w][c][l31]      = aB0[r];
        OT[w][c + 32][l31] = aB1[r];
    }
    __syncthreads();
    {
        const int c = t >> 3, q0 = (t & 7) * 4;
        f32x4 o = {0.f, 0.f, 0.f, 0.f};
        f32x4 ls = {0.f, 0.f, 0.f, 0.f};
        #pragma unroll
        for (int p = 0; p < 8; ++p) {
            const f32x4 v = *(const f32x4*)&OT[p][c][q0];
            o[0] += v[0]; o[1] += v[1]; o[2] += v[2]; o[3] += v[3];
            #pragma unroll
            for (int k = 0; k < 4; ++k) ls[k] += LC[1][p][q0 + k];
        }
        const size_t off = ((size_t)b * C_ + c) * N_ + i0 + 32 + q0;
        const float4 xv = *(const float4*)(x + off);
        float4 res;
        res.x = la * o[0] / ls[0] + xv.x;
        res.y = la * o[1] / ls[1] + xv.y;
        res.z = la * o[2] / ls[2] + xv.z;
        res.w = la * o[3] / ls[3] + xv.w;
        *(float4*)(out + off) = res;
    }
}

extern "C" void kernel_launch(void* const* d_in, const int* in_sizes, int n_in,
                              void* d_out, int out_size, void* d_ws, size_t ws_size,
                              hipStream_t stream)
{
    (void)in_sizes; (void)n_in; (void)out_size; (void)ws_size;
    const float* x    = (const float*)d_in[0];
    const float* xrgb = (const float*)d_in[1];
    const float* Wq   = (const float*)d_in[2];
    const float* bq   = (const float*)d_in[3];
    const float* Wk   = (const float*)d_in[4];
    const float* bk   = (const float*)d_in[5];
    const float* Wv   = (const float*)d_in[6];
    const float* bv   = (const float*)d_in[7];
    const float* lam  = (const float*)d_in[8];
    float* out = (float*)d_out;

    // workspace (bf16): Q 512KB | K 512KB | VT 2MB — all fully overwritten
    ushort* Qw = (ushort*)d_ws;                       // [B][N][16]
    ushort* Kw = Qw + (size_t)B_ * N_ * 16;           // [B][N][16]
    ushort* Vw = Kw + (size_t)B_ * N_ * 16;           // VT[B][N/16][64][16]

    qkv_mfma<<<dim3(N_ / 32, B_), 256, 0, stream>>>(
        x, xrgb, Wq, bq, Wk, bk, Wv, bv, Qw, Kw, Vw);

    flash32<<<dim3(256), 512, 0, stream>>>(
        Qw, Kw, Vw, x, lam, out);
}

// Round 13
// 36.410 us; speedup vs baseline: 1.0550x; 1.0422x over previous
//
#include <hip/hip_runtime.h>
#include <hip/hip_bf16.h>
#include <math.h>

#define B_   4
#define C_   64
#define N_   4096
#define L2E  1.4426950408889634f

typedef __attribute__((ext_vector_type(8)))  short bf16x8;
typedef __attribute__((ext_vector_type(4)))  float f32x4;
typedef __attribute__((ext_vector_type(16))) float f32x16;
typedef __attribute__((ext_vector_type(4)))  uint  uint4v;

#define MFMA16(a,b,c) __builtin_amdgcn_mfma_f32_16x16x32_bf16(a,b,c,0,0,0)
#define MFMA32(a,b,c) __builtin_amdgcn_mfma_f32_32x32x16_bf16(a,b,c,0,0,0)

static __device__ inline ushort f2bf(float f) {
    __hip_bfloat16 h = __float2bfloat16(f);
    return *reinterpret_cast<ushort*>(&h);
}
static __device__ inline uint packbf(float a, float b) {
    return (uint)f2bf(a) | ((uint)f2bf(b) << 16);
}
static __device__ inline uint cvtpk(float lo, float hi) {
    uint r;
    asm("v_cvt_pk_bf16_f32 %0, %1, %2" : "=v"(r) : "v"(lo), "v"(hi));
    return r;
}
static __device__ inline void plswap(uint &a, uint &b) {
    asm("v_permlane32_swap_b32 %0, %1" : "+v"(a), "+v"(b));
}
static __device__ inline float tsum16(const f32x16 &s) {
    float a0 = s[0] + s[1],  a1 = s[2] + s[3];
    float a2 = s[4] + s[5],  a3 = s[6] + s[7];
    float a4 = s[8] + s[9],  a5 = s[10] + s[11];
    float a6 = s[12] + s[13], a7 = s[14] + s[15];
    a0 += a1; a2 += a3; a4 += a5; a6 += a7;
    return (a0 + a2) + (a4 + a6);
}

// ---------------- QKV projection: zero-LDS, zero-barrier (R10, validated) ---
__global__ __launch_bounds__(256) void qkv_mfma(
    const float* __restrict__ x, const float* __restrict__ xrgb,
    const float* __restrict__ Wq, const float* __restrict__ bq,
    const float* __restrict__ Wk, const float* __restrict__ bk,
    const float* __restrict__ Wv, const float* __restrict__ bv,
    ushort* __restrict__ Qo, ushort* __restrict__ Ko, ushort* __restrict__ Vo)
{
    const int t = threadIdx.x, b = blockIdx.y, n0 = blockIdx.x * 32;
    const int w = t >> 6, lane = t & 63, li = lane & 15, g = lane >> 4;
    const int pw = w & 1, oh = w >> 1;

    const int px = n0 + pw * 16 + li;

    bf16x8 bxf[2], brf[2];
    #pragma unroll
    for (int kk = 0; kk < 2; ++kk) {
        const int c0 = kk * 32 + g * 8;
        const float* xb = x + ((size_t)b * C_ + c0) * N_ + px;
        #pragma unroll
        for (int r = 0; r < 8; ++r) bxf[kk][r] = (short)f2bf(xb[(size_t)r * N_]);
        if (oh == 0) {
            const float* rb = xrgb + ((size_t)b * C_ + c0) * N_ + px;
            #pragma unroll
            for (int r = 0; r < 8; ++r) brf[kk][r] = (short)f2bf(rb[(size_t)r * N_]);
        } else {
            brf[kk] = bxf[kk];   // never used for ot!=0, keep defined
        }
    }

    const f32x4 cz = {0.f, 0.f, 0.f, 0.f};
    #pragma unroll
    for (int j = 0; j < 3; ++j) {
        const int ot = oh * 3 + j;
        const float* wsrc;
        const float* bsrc;
        if (ot == 0)      { wsrc = Wq + li * 64;                   bsrc = bq; }
        else if (ot == 1) { wsrc = Wk + li * 64;                   bsrc = bk; }
        else              { wsrc = Wv + ((ot - 2) * 16 + li) * 64; bsrc = bv + (ot - 2) * 16; }
        const float s = (ot == 0) ? L2E : 1.0f;   // fold log2e into Q

        f32x4 acc = cz;
        #pragma unroll
        for (int kk = 0; kk < 2; ++kk) {
            const int c0 = kk * 32 + g * 8;
            const float4 a  = *(const float4*)(wsrc + c0);
            const float4 c4 = *(const float4*)(wsrc + c0 + 4);
            bf16x8 wa;
            wa[0] = (short)f2bf(a.x * s);  wa[1] = (short)f2bf(a.y * s);
            wa[2] = (short)f2bf(a.z * s);  wa[3] = (short)f2bf(a.w * s);
            wa[4] = (short)f2bf(c4.x * s); wa[5] = (short)f2bf(c4.y * s);
            wa[6] = (short)f2bf(c4.z * s); wa[7] = (short)f2bf(c4.w * s);
            acc = MFMA16(wa, (ot == 0 ? brf[kk] : bxf[kk]), acc);
        }
        const float b0 = bsrc[g * 4 + 0] * s, b1 = bsrc[g * 4 + 1] * s;
        const float b2 = bsrc[g * 4 + 2] * s, b3 = bsrc[g * 4 + 3] * s;
        if (ot < 2) {
            uint2 pwd;
            pwd.x = packbf(acc[0] + b0, acc[1] + b1);
            pwd.y = packbf(acc[2] + b2, acc[3] + b3);
            ushort* dst = (ot == 0 ? Qo : Ko) + (size_t)(b * N_ + px) * 16 + g * 4;
            *(uint2*)dst = pwd;
        } else {
            const size_t base = (((size_t)b * (N_ / 16) + (px >> 4)) * 64
                                 + (ot - 2) * 16 + g * 4) * 16 + (px & 15);
            Vo[base]      = f2bf(acc[0] + b0);
            Vo[base + 16] = f2bf(acc[1] + b1);
            Vo[base + 32] = f2bf(acc[2] + b2);
            Vo[base + 48] = f2bf(acc[3] + b3);
        }
    }
}

// ---------------- flash attention: 16 waves/block (4/SIMD) -----------------
// 256 blocks x 1024 thr; wave w = (qh = w&1 query-half) x (jg = w>>1 of 8
// key-groups, 512 keys each, 16 tiles of 32). One Q-frag/wave (~90 VGPR, no
// spill at the 128 cap). qh-pairs of a jg share K/V streams -> L1 absorbs
// the re-read. No-shift softmax (|s*log2e| << 126 -> raw exp2, pure-sum
// merge; validated R12). Single-round 16-partial merge, 2 barriers.
__global__ __launch_bounds__(1024, 4) void flash32(
    const ushort* __restrict__ Qg, const ushort* __restrict__ Kg,
    const ushort* __restrict__ VT, const float* __restrict__ x,
    const float* __restrict__ lam, float* __restrict__ out)
{
    __shared__ float OT[16][64][33];  // 135168 B: [qh*8+jg][c][q] partial O
    __shared__ float LC[16][33];      // 2112 B: partial l

    const int t = threadIdx.x, w = t >> 6, lane = t & 63;
    const int l31 = lane & 31, h = lane >> 5;
    const int qh = w & 1, jg = w >> 1;

    const int wg = blockIdx.x;
    const int b  = wg >> 6;
    const int i0 = (wg & 63) * 64;

    // Q fragment: queries i0 + qh*32 + l31 (B op: col=q, k=h*8+r)
    const bf16x8 qf = *(const bf16x8*)(Qg + ((size_t)(b * N_ + i0 + qh * 32 + l31)) * 16 + h * 8);

    const size_t jbase = (size_t)jg * 512;
    const ushort* kp = Kg + ((size_t)(b * N_) + jbase + l31) * 16 + h * 8;
    const ushort* vt = VT + (((size_t)b * (N_ / 16) + jg * 32) * 64 + l31) * 16 + h * 8;

    f32x16 a0, a1, z16;
    #pragma unroll
    for (int i = 0; i < 16; ++i) { a0[i] = 0.f; a1[i] = 0.f; z16[i] = 0.f; }
    float lsum = 0.f;

    #pragma unroll 1
    for (int jt = 0; jt < 16; ++jt) {          // 16 tiles of 32 keys
        const bf16x8 kf = *(const bf16x8*)(kp + (size_t)jt * 512);

        f32x16 st = MFMA32(kf, qf, z16);
        #pragma unroll
        for (int i = 0; i < 16; ++i) st[i] = exp2f(st[i]);   // raw 2^s (no shift)
        lsum += tsum16(st);

        // P -> bf16 PV fragments in-register (T12, validated R7-R12)
        uint A0 = cvtpk(st[0],  st[1]),  A1 = cvtpk(st[2],  st[3]);
        uint B0 = cvtpk(st[4],  st[5]),  B1 = cvtpk(st[6],  st[7]);
        uint C0 = cvtpk(st[8],  st[9]),  C1 = cvtpk(st[10], st[11]);
        uint D0 = cvtpk(st[12], st[13]), D1 = cvtpk(st[14], st[15]);
        plswap(A0, B0); plswap(A1, B1); plswap(C0, D0); plswap(C1, D1);
        uint4v u0 = {A0, A1, B0, B1}, u1 = {C0, C1, D0, D1};
        const bf16x8 pf0 = __builtin_bit_cast(bf16x8, u0);
        const bf16x8 pf1 = __builtin_bit_cast(bf16x8, u1);

        // PV: V fragments 2-at-a-time (keeps live set small)
        const ushort* vtj = vt + (size_t)jt * 2048;
        {
            const bf16x8 va = *(const bf16x8*)(vtj);
            const bf16x8 vb = *(const bf16x8*)(vtj + 512);
            a0 = MFMA32(va, pf0, a0);
            a1 = MFMA32(vb, pf0, a1);
        }
        {
            const bf16x8 va = *(const bf16x8*)(vtj + 1024);
            const bf16x8 vb = *(const bf16x8*)(vtj + 1536);
            a0 = MFMA32(va, pf1, a0);
            a1 = MFMA32(vb, pf1, a1);
        }
    }

    // per-query l (combine C/D row-halves h=0/1)
    lsum += __shfl_xor(lsum, 32);
    if (h == 0) LC[w][l31] = lsum;

    // write partial O
    #pragma unroll
    for (int r = 0; r < 16; ++r) {
        const int c = (r & 3) + 8 * (r >> 2) + 4 * h;
        OT[w][c][l31]      = a0[r];
        OT[w][c + 32][l31] = a1[r];
    }
    __syncthreads();

    // ---- single-round merge: thread -> (qh2, c, 4 queries) ----
    {
        const int qh2 = t >> 9, c = (t >> 3) & 63, q0 = (t & 7) * 4;
        const float la = lam[0];
        f32x4 o = {0.f, 0.f, 0.f, 0.f};
        f32x4 ls = {0.f, 0.f, 0.f, 0.f};
        #pragma unroll
        for (int p = 0; p < 8; ++p) {
            const int idx = p * 2 + qh2;          // wave (qh2, jg=p)
            const f32x4 v = *(const f32x4*)&OT[idx][c][q0];
            o[0] += v[0]; o[1] += v[1]; o[2] += v[2]; o[3] += v[3];
            #pragma unroll
            for (int k = 0; k < 4; ++k) ls[k] += LC[idx][q0 + k];
        }
        const size_t off = ((size_t)b * C_ + c) * N_ + i0 + qh2 * 32 + q0;
        const float4 xv = *(const float4*)(x + off);
        float4 res;
        res.x = la * o[0] / ls[0] + xv.x;
        res.y = la * o[1] / ls[1] + xv.y;
        res.z = la * o[2] / ls[2] + xv.z;
        res.w = la * o[3] / ls[3] + xv.w;
        *(float4*)(out + off) = res;
    }
}

extern "C" void kernel_launch(void* const* d_in, const int* in_sizes, int n_in,
                              void* d_out, int out_size, void* d_ws, size_t ws_size,
                              hipStream_t stream)
{
    (void)in_sizes; (void)n_in; (void)out_size; (void)ws_size;
    const float* x    = (const float*)d_in[0];
    const float* xrgb = (const float*)d_in[1];
    const float* Wq   = (const float*)d_in[2];
    const float* bq   = (const float*)d_in[3];
    const float* Wk   = (const float*)d_in[4];
    const float* bk   = (const float*)d_in[5];
    const float* Wv   = (const float*)d_in[6];
    const float* bv   = (const float*)d_in[7];
    const float* lam  = (const float*)d_in[8];
    float* out = (float*)d_out;

    // workspace (bf16): Q 512KB | K 512KB | VT 2MB — all fully overwritten
    ushort* Qw = (ushort*)d_ws;                       // [B][N][16]
    ushort* Kw = Qw + (size_t)B_ * N_ * 16;           // [B][N][16]
    ushort* Vw = Kw + (size_t)B_ * N_ * 16;           // VT[B][N/16][64][16]

    qkv_mfma<<<dim3(N_ / 32, B_), 256, 0, stream>>>(
        x, xrgb, Wq, bq, Wk, bk, Wv, bv, Qw, Kw, Vw);

    flash32<<<dim3(256), 1024, 0, stream>>>(
        Qw, Kw, Vw, x, lam, out);
}